// Round 1
// baseline (231.803 us; speedup 1.0000x reference)
//
#include <hip/hip_runtime.h>
#include <hip/hip_bf16.h>

#define NH 96          // heads
#define NE 1537        // edge table rows
#define ND 5           // multi-hop
#define NN 128         // nodes
#define NB 16          // batch
#define NP1 129        // N+1
#define OUT_PLANE (NP1 * NP1)   // 16641

__device__ __forceinline__ float bflo(unsigned u) { return __uint_as_float(u << 16); }
__device__ __forceinline__ float bfhi(unsigned u) { return __uint_as_float(u & 0xffff0000u); }

// ---------------------------------------------------------------------------
// Kernel 1: M[d][e][h] = sum_k edge_enc_w[e][k] * W[d][k][h], stored bf16 (RTNE)
// W[d][k][h] = edge_dis_w[(d*32+k)*96 + h]
// ---------------------------------------------------------------------------
__global__ __launch_bounds__(256) void k_build_M(
    const float* __restrict__ E, const float* __restrict__ Wd,
    unsigned short* __restrict__ M) {
  int o = blockIdx.x * 256 + threadIdx.x;
  if (o >= ND * NE * NH) return;
  int h = o % NH;
  int r = o / NH;
  int e = r % NE;
  int d = r / NE;
  const float* __restrict__ Er = E + e * 32;
  const float* __restrict__ Wp = Wd + d * 32 * NH + h;
  float acc = 0.f;
#pragma unroll
  for (int k = 0; k < 32; ++k) acc = fmaf(Er[k], Wp[k * NH], acc);
  unsigned u = __float_as_uint(acc);
  unsigned rb = (u + 0x7fffu + ((u >> 16) & 1u)) >> 16;   // round-to-nearest-even
  M[o] = (unsigned short)rb;
}

// ---------------------------------------------------------------------------
// Kernel 2: interior cells (i>=1, j>=1).
// Block = (b, i) row x 64-wide j tile. 256 threads = 64 pairs x 4 head-quarters.
// ---------------------------------------------------------------------------
__global__ __launch_bounds__(256) void k_interior(
    const float* __restrict__ ab, const int* __restrict__ spos,
    const int* __restrict__ eidx, const float* __restrict__ spw,
    const unsigned short* __restrict__ M, float* __restrict__ out) {
  const int jt = blockIdx.x;   // 0..1
  const int n  = blockIdx.y;   // 0..127  (i-1)
  const int b  = blockIdx.z;   // 0..15
  const int i  = n + 1;
  const int j0 = jt * 64;

  __shared__ int   s_idx[960];       // 64 pairs x 15 edge indices
  __shared__ int   s_sp[64];
  __shared__ float s_eb[64][97];     // pad 97: phase-2 reads conflict-free

  const int tid = threadIdx.x;
  const int pairbase = (b * NN + n) * NN + j0;
  const int* __restrict__ ebase = eidx + pairbase * 15;
  for (int k = tid; k < 960; k += 256) s_idx[k] = ebase[k];
  if (tid < 64) s_sp[tid] = spos[pairbase + tid];
  __syncthreads();

  const int p  = tid >> 2;     // pair within tile
  const int q  = tid & 3;      // head quarter
  const int hq = q * 24;       // 24 heads = 12 bf16x2 dwords = 48 B

  float acc[24];
#pragma unroll
  for (int c = 0; c < 24; ++c) acc[c] = 0.f;

  const int* mi = s_idx + p * 15;
#pragma unroll
  for (int g = 0; g < 15; ++g) {
    const int d = g / 3;                       // constant after unroll
    const int e = mi[g];
    const uint4* __restrict__ r = (const uint4*)(M + (d * NE + e) * NH + hq);
    uint4 a0 = r[0], a1 = r[1], a2 = r[2];
    unsigned w[12] = {a0.x, a0.y, a0.z, a0.w, a1.x, a1.y, a1.z, a1.w,
                      a2.x, a2.y, a2.z, a2.w};
#pragma unroll
    for (int c = 0; c < 12; ++c) {
      acc[2 * c]     += bflo(w[c]);
      acc[2 * c + 1] += bfhi(w[c]);
    }
  }

  // hop normalizer: sp = clamp(spatial_pos - 1, 1, 5)
  const int spn = s_sp[p];
  const int spc = min(max(spn - 1, 1), 5);
  const float scale = 1.0f / (3.0f * (float)spc);

  // spatial positional bias gather (fp32 table, row = 96 floats)
  const float4* __restrict__ sr = (const float4*)(spw + spn * NH + hq);
  float4 sv4[6];
#pragma unroll
  for (int c = 0; c < 6; ++c) sv4[c] = sr[c];
  const float* sv = (const float*)sv4;

#pragma unroll
  for (int c = 0; c < 24; ++c) s_eb[p][hq + c] = acc[c] * scale + sv[c];
  __syncthreads();

  // phase 2: lanes along j -> coalesced writes; h uniform per wave
  const int jl = tid & 63;
  const int hb = tid >> 6;     // 0..3
  const float a2v = 2.0f * ab[(b * NP1 + i) * NP1 + 1 + j0 + jl];
  const int obase = i * NP1 + 1 + j0 + jl;
#pragma unroll
  for (int it = 0; it < 24; ++it) {
    const int h = it * 4 + hb;
    const float v = s_eb[jl][h] + a2v;
    out[((h >> 3) * 128 + b * 8 + (h & 7)) * OUT_PLANE + obase] = v;
  }
}

// ---------------------------------------------------------------------------
// Kernel 3: boundary cells: row i=0 (all j) and column j=0 (i>=1):
//   out = 2*attn_bias + virt_w[h]
// ---------------------------------------------------------------------------
__global__ __launch_bounds__(512) void k_boundary(
    const float* __restrict__ ab, const float* __restrict__ virt,
    float* __restrict__ out) {
  const int bh = blockIdx.x;   // 0..1535 = b*96+h
  const int b = bh / NH;
  const int h = bh % NH;
  const float t = virt[h];
  const int tid = threadIdx.x;
  const int base = ((h >> 3) * 128 + b * 8 + (h & 7)) * OUT_PLANE;
  if (tid < NP1) {
    out[base + tid] = 2.f * ab[(b * NP1) * NP1 + tid] + t;
  } else if (tid < NP1 + NN) {
    const int i = tid - 128;   // 1..128
    out[base + i * NP1] = 2.f * ab[(b * NP1 + i) * NP1] + t;
  }
}

// ---------------------------------------------------------------------------
extern "C" void kernel_launch(void* const* d_in, const int* in_sizes, int n_in,
                              void* d_out, int out_size, void* d_ws, size_t ws_size,
                              hipStream_t stream) {
  const float* ab   = (const float*)d_in[0];   // attn_bias     [16,129,129] f32
  const int*   spos = (const int*)d_in[1];     // spatial_pos   [16,128,128] i32
  // d_in[2] node_attr: unused by reference math
  const int*   eidx = (const int*)d_in[3];     // edge_input    [16,128,128,5,3] i32
  const float* eenc = (const float*)d_in[4];   // edge_enc_w    [1537,32] f32
  const float* edis = (const float*)d_in[5];   // edge_dis_w    [393216,1] f32
  const float* spw  = (const float*)d_in[6];   // spatial_enc_w [522,96] f32
  const float* virt = (const float*)d_in[7];   // virt_w        [1,96] f32
  float* out = (float*)d_out;

  unsigned short* M = (unsigned short*)d_ws;   // 5*1537*96 bf16 = 1.48 MB

  const int totM = ND * NE * NH;
  k_build_M<<<(totM + 255) / 256, 256, 0, stream>>>(eenc, edis, M);
  k_interior<<<dim3(2, NN, NB), 256, 0, stream>>>(ab, spos, eidx, spw, M, out);
  k_boundary<<<NB * NH, 512, 0, stream>>>(ab, virt, out);
}